// Round 15
// baseline (56.775 us; speedup 1.0000x reference)
//
#include <hip/hip_runtime.h>
#include <cstdint>

// FCOS post-processor, MI355X — round 15.
// R14 postmortem: k_fcr_nms = 45us, FETCH 4.35MB at 100 GB/s on 16 blocks —
// the ~4MB of scattered reg[] single-float gathers (1005 cand x 4 planes x 16
// img) had no parallelism to hide ~900cy HBM misses. Fix: decode boxes in
// k_scanstore (960 blocks hide the gather), store SoA prelists:
//   preval f32 (raw sm — selection ignores validity, like the reference),
//   pregi  u32 (top_k tie-break), prebox float4 (invalid = (-1,-1,-1,-1):
//   zero-area -> never suppresses; x<0 flags score masking).
// k_fcr_nms's global traffic is now just coalesced prelist streams.
//
//  k_scanstore : read cls+ctr once (31 MB). Per block: 512-bin LDS hist ->
//                local thresh (suffix>=128) -> prelist; gather reg + decode
//                + clip + keep_size -> (val, gi, box) per entry.
//  k_fcr_nms   : per image, 1024 thr: offs-scan; pass1 bucket 2048-hist of
//                preval -> boundary bucket B2; bases; pass2 scatter cand ->
//                sk (keys) + skbox; exact rank (val desc, idx asc == jax
//                top_k); spatial-hash NMS; exact greedy; select 100; write.

#define NIMG 16
#define WW 608
#define HW 243200
#define NF4 60800          // HW/4
#define TOPK 1000
#define NBINS 512          // scanstore local hist bins
#define NB2 2048           // fine buckets (selection + sort)
#define SCAN_BLOCKS 60     // per image
#define SCAN_THREADS 256
#define F4_PER_BLOCK 1024  // 60*1024*4 = 245760 >= 243200
#define LS 128             // local-suffix constant for prelist threshold
#define PCAP 1024          // prelist cap per scan block (~136 expected)
#define MCAP 2048          // candidate cap per image (expected ~1005)
#define EDS_CAP 512        // edge cap (observed ~15/image)
#define NEGV (-1e9f)

__device__ __forceinline__ float sigm(float x) { return 1.0f / (1.0f + expf(-x)); }

__device__ __forceinline__ int binof(float v) {
  if (!(v > 0.0f)) return 0;
  int b = (int)(v * (float)NBINS);
  return b > (NBINS - 1) ? (NBINS - 1) : b;
}

__device__ __forceinline__ int bucketof(float v) {
  if (!(v > 0.0f)) return 0;
  int b = (int)(v * (float)NB2);
  return b > (NB2 - 1) ? (NB2 - 1) : b;
}

// wave0 (tid<64): *outbs = max b with suffix_bins(b) >= T, else 0 (512 bins).
__device__ __forceinline__ void find_thresh_bin(const unsigned* h, const unsigned* chunk,
                                                unsigned T, unsigned* outbs, int tid) {
  unsigned v = (tid < 32) ? chunk[tid] : 0u;
  unsigned inc = v;
#pragma unroll
  for (int d = 1; d < 32; d <<= 1) {
    unsigned o = __shfl_down(inc, d, 64);
    if (tid + d < 32) inc += o;
  }
  unsigned long long m = __ballot((tid < 32) && (inc >= T));
  if (m == 0ull) { if (tid == 0) *outbs = 0u; return; }
  int cc = 63 - __clzll(m);
  unsigned above = __shfl(inc, cc) - chunk[cc];
  unsigned v2 = (tid < 16) ? h[cc * 16 + tid] : 0u;
  unsigned inc2 = v2;
#pragma unroll
  for (int d = 1; d < 16; d <<= 1) {
    unsigned o = __shfl_down(inc2, d, 64);
    if (tid + d < 16) inc2 += o;
  }
  unsigned long long m2 = __ballot((tid < 16) && (above + inc2 >= T));
  int bb = (m2 != 0ull) ? (63 - __clzll(m2)) : 0;
  if (tid == 0) *outbs = (unsigned)(cc * 16 + bb);
}

__global__ __launch_bounds__(SCAN_THREADS) void k_scanstore(
    const float4* __restrict__ cls, const float4* __restrict__ ctr,
    const float* __restrict__ reg, const int* __restrict__ isz,
    float* __restrict__ preval, unsigned* __restrict__ pregi,
    float4* __restrict__ prebox, unsigned* __restrict__ pcnt) {
  __shared__ unsigned lh[NBINS];
  __shared__ float lval[PCAP];
  __shared__ unsigned lgi[PCAP];
  __shared__ unsigned chunk[NBINS / 16];
  __shared__ unsigned sLb, pcl;
  const int tid = threadIdx.x;
  for (int b = tid; b < NBINS; b += SCAN_THREADS) lh[b] = 0u;
  if (tid == 0) pcl = 0u;
  __syncthreads();
  const int n = blockIdx.y;
  const float4* c4 = cls + (size_t)n * NF4;
  const float4* t4 = ctr + (size_t)n * NF4;
  const int base = blockIdx.x * F4_PER_BLOCK;
  float4 cv[4], tv[4];
  float smr[16];
  bool ok[4];
#pragma unroll
  for (int e = 0; e < 4; ++e) {
    int i = base + e * SCAN_THREADS + tid;
    ok[e] = (i < NF4);
    if (ok[e]) { cv[e] = c4[i]; tv[e] = t4[i]; }
  }
#pragma unroll
  for (int e = 0; e < 4; ++e) {
    const float* cc = (const float*)&cv[e];
    const float* tt = (const float*)&tv[e];
#pragma unroll
    for (int k = 0; k < 4; ++k) {
      float sm = NEGV;
      if (ok[e]) {
        float sc = sigm(cc[k]);
        sm = (sc > 0.05f) ? sc * sigm(tt[k]) : NEGV;
        atomicAdd(&lh[binof(sm)], 1u);  // LDS atomic
      }
      smr[e * 4 + k] = sm;
    }
  }
  __syncthreads();
  if (tid < NBINS / 16) {
    unsigned s = 0;
    for (int k = 0; k < 16; ++k) s += lh[tid * 16 + k];
    chunk[tid] = s;
  }
  __syncthreads();
  if (tid < 64) find_thresh_bin(lh, chunk, LS, &sLb, tid);
  __syncthreads();
  const unsigned Lb = sLb;
#pragma unroll
  for (int e = 0; e < 4; ++e) {
    if (ok[e]) {
#pragma unroll
      for (int k = 0; k < 4; ++k) {
        float sm = smr[e * 4 + k];
        if ((unsigned)binof(sm) >= Lb) {
          unsigned gi = (unsigned)((base + e * SCAN_THREADS + tid) * 4 + k);
          unsigned p = atomicAdd(&pcl, 1u);  // LDS atomic
          if (p < PCAP) { lval[p] = sm; lgi[p] = gi; }
        }
      }
    }
  }
  __syncthreads();
  const int bslot = n * SCAN_BLOCKS + blockIdx.x;
  unsigned m = pcl; if (m > PCAP) m = PCAP;
  // gather reg + decode + clip + keep_size; 960 blocks hide the scattered loads
  const float wmax = (float)(isz[n * 2 + 1] - 1);
  const float hmax = (float)(isz[n * 2 + 0] - 1);
  const float* rg = reg + (size_t)n * 4 * HW;
  const size_t gbase = (size_t)bslot * PCAP;
  for (unsigned k = tid; k < m; k += SCAN_THREADS) {
    unsigned gi = lgi[k];
    float val = lval[k];
    int wx = (int)gi % WW, hy = (int)gi / WW;
    float lx = (float)(wx * 8 + 4), ly = (float)(hy * 8 + 4);
    float l = rg[0 * HW + gi], tt = rg[1 * HW + gi];
    float rr = rg[2 * HW + gi], bb = rg[3 * HW + gi];
    float x1 = lx - l, y1 = ly - tt, x2 = lx + rr, y2 = ly + bb;
    x1 = fminf(fmaxf(x1, 0.0f), wmax);
    x2 = fminf(fmaxf(x2, 0.0f), wmax);
    y1 = fminf(fmaxf(y1, 0.0f), hmax);
    y2 = fminf(fmaxf(y2, 0.0f), hmax);
    bool valid = (((x2 - x1 + 1.0f) >= 0.0f) && ((y2 - y1 + 1.0f) >= 0.0f));
    float4 bx = valid ? make_float4(x1, y1, x2, y2)
                      : make_float4(-1.f, -1.f, -1.f, -1.f);  // zero-area, x<0 flag
    preval[gbase + k] = val;
    pregi[gbase + k] = gi;
    prebox[gbase + k] = bx;
  }
  if (tid == 0) pcnt[bslot] = m;
}

// selection + rank + spatial-hash NMS + output: one 1024-thread block per image.
__global__ __launch_bounds__(1024) void k_fcr_nms(
    const float* __restrict__ preval, const unsigned* __restrict__ pregi,
    const float4* __restrict__ prebox, const unsigned* __restrict__ pcnt,
    const int* __restrict__ isz, float* __restrict__ out) {
  __shared__ __align__(16) unsigned long long smemA[2816];  // 22.5 KB: sb/ssc/kept/sel
  __shared__ __align__(16) unsigned long long sk[MCAP];     // 16 KB
  __shared__ __align__(16) float4 skbox[MCAP];              // 32 KB
  __shared__ unsigned bh[NB2];                              // 8 KB
  __shared__ unsigned bbase[NB2];                           // 8 KB
  __shared__ unsigned chunk[32];
  __shared__ unsigned offs[SCAN_BLOCKS + 1];
  __shared__ unsigned wsum[16];
  __shared__ unsigned sB2, mc, ecl;
  const int n = blockIdx.x;
  const int tid = threadIdx.x;
  const int wid = tid >> 6, lane = tid & 63;

  for (int b = tid; b < NB2; b += 1024) bh[b] = 0u;
  if (tid < 64) {  // wave0: shfl-scan prelist counts
    int l = tid;
    int v = (l < SCAN_BLOCKS) ? (int)pcnt[n * SCAN_BLOCKS + l] : 0;
    int inc = v;
#pragma unroll
    for (int d = 1; d < 64; d <<= 1) {
      int o = __shfl_up(inc, d, 64);
      if (l >= d) inc += o;
    }
    if (l < SCAN_BLOCKS) offs[l + 1] = (unsigned)inc;
    if (l == 0) offs[0] = 0u;
  }
  __syncthreads();
  const unsigned P = offs[SCAN_BLOCKS];
  const size_t ibase = (size_t)n * SCAN_BLOCKS * PCAP;
  // ---- pass 1: bucket hist of all prelist vals (coalesced f32 stream) ----
  for (unsigned p = tid; p < P; p += 1024) {
    int lo = 0, hi = SCAN_BLOCKS - 1;
    while (lo < hi) {
      int mid = (lo + hi + 1) >> 1;
      if (offs[mid] <= p) lo = mid; else hi = mid - 1;
    }
    float v = preval[ibase + (size_t)lo * PCAP + (p - offs[lo])];
    atomicAdd(&bh[bucketof(v)], 1u);
  }
  __syncthreads();
  // ---- boundary bucket B2 = max bucket with suffix >= TOPK ----
  if (tid < 32) {
    unsigned s = 0;
    const int b0 = tid * 64;
    for (int k = 0; k < 64; ++k) s += bh[b0 + k];
    chunk[tid] = s;
  }
  __syncthreads();
  if (tid < 64) {
    unsigned v = (tid < 32) ? chunk[tid] : 0u;
    unsigned inc = v;
#pragma unroll
    for (int d = 1; d < 32; d <<= 1) {
      unsigned o = __shfl_down(inc, d, 64);
      if (tid + d < 32) inc += o;
    }
    unsigned long long m = __ballot((tid < 32) && (inc >= TOPK));
    int cc = (m != 0ull) ? (63 - __clzll(m)) : 0;
    unsigned above = (m != 0ull) ? (__shfl(inc, cc) - chunk[cc]) : 0u;
    unsigned inc2 = bh[cc * 64 + tid];
#pragma unroll
    for (int d = 1; d < 64; d <<= 1) {
      unsigned o = __shfl_down(inc2, d, 64);
      if (tid + d < 64) inc2 += o;
    }
    unsigned long long m2 = __ballot(above + inc2 >= TOPK);
    int bb = (m2 != 0ull) ? (63 - __clzll(m2)) : 0;
    if (tid == 0) sB2 = (m != 0ull) ? (unsigned)(cc * 64 + bb) : 0u;
  }
  __syncthreads();
  const unsigned B2 = sB2;
  // ---- descending bucket bases: bbase[b] = #vals in buckets > b ----
  {
    int g0 = tid * 2, g1 = g0 + 1;
    unsigned a0 = bh[NB2 - 1 - g0];
    unsigned a1 = bh[NB2 - 1 - g1];
    unsigned pair = a0 + a1;
    unsigned inc = pair;
#pragma unroll
    for (int d = 1; d < 64; d <<= 1) {
      unsigned o = __shfl_up(inc, d, 64);
      if (lane >= d) inc += o;
    }
    if (lane == 63) wsum[wid] = inc;
    __syncthreads();
    if (tid < 64) {
      unsigned v = (tid < 16) ? wsum[tid] : 0u;
      unsigned i2 = v;
#pragma unroll
      for (int d = 1; d < 16; d <<= 1) {
        unsigned o = __shfl_up(i2, d, 64);
        if (tid >= d) i2 += o;
      }
      if (tid < 16) wsum[tid] = i2 - v;
    }
    __syncthreads();
    unsigned excl = inc - pair + wsum[wid];
    bbase[NB2 - 1 - g0] = excl;
    bbase[NB2 - 1 - g1] = excl + a0;
  }
  __syncthreads();
  if (tid == 0) {
    unsigned mm = bbase[B2] + bh[B2];
    mc = (mm > MCAP) ? MCAP : mm;
  }
  for (int b = tid; b < NB2; b += 1024) bh[b] = 0u;  // scatter counters
  __syncthreads();
  const unsigned M = mc;
  // ---- pass 2: scatter candidates (bucket >= B2) -> sk (keys) + skbox ----
  for (unsigned p = tid; p < P; p += 1024) {
    int lo = 0, hi = SCAN_BLOCKS - 1;
    while (lo < hi) {
      int mid = (lo + hi + 1) >> 1;
      if (offs[mid] <= p) lo = mid; else hi = mid - 1;
    }
    size_t idx = ibase + (size_t)lo * PCAP + (p - offs[lo]);
    float v = preval[idx];
    int b = bucketof(v);
    if ((unsigned)b >= B2) {
      unsigned gi = pregi[idx];
      unsigned pos = bbase[b] + atomicAdd(&bh[b], 1u);
      if (pos < MCAP) {
        sk[pos] = ((unsigned long long)__float_as_uint(v) << 32) |
                  (unsigned long long)(~gi);
        skbox[pos] = prebox[idx];
      }
    }
  }
  // ---- prefill output boxes/scores (overlay smemA) ----
  float4* sb = (float4*)smemA;                                   // 16000 B
  float* ssc = (float*)((char*)smemA + 16384);                   // 4000 B
  unsigned char* kept = (unsigned char*)((char*)smemA + 20480);  // 1000 B
  int* sel = (int*)((char*)smemA + 21600);                       // 400 B
  if (tid < TOPK) { sb[tid] = make_float4(0.f, 0.f, 0.f, 0.f); ssc[tid] = NEGV; }
  __syncthreads();
  // ---- exact rank (bucket base + same-bucket u64 count) + place into sb ----
  for (unsigned s = tid; s < M; s += 1024) {
    const unsigned long long mykey = sk[s];
    const float val = __uint_as_float((unsigned)(mykey >> 32));
    int b = bucketof(val);
    unsigned beg = bbase[b];
    unsigned end = (b > 0) ? bbase[b - 1] : M;
    if (end > M) end = M;
    unsigned rank = beg;
    for (unsigned t = beg; t < end; ++t) rank += (sk[t] > mykey) ? 1u : 0u;
    if (rank >= TOPK) continue;
    float4 bx = skbox[s];
    sb[rank] = bx;
    ssc[rank] = (bx.x < 0.0f) ? NEGV : val;  // keep_size-invalid -> masked score
  }
  __syncthreads();
  // ---- spatial-hash NMS (bh/bbase free): boxes <128px -> 3x3 cell checks ----
  unsigned* ccount = bh;
  unsigned* cidx = bh + 1024;
  unsigned* cbase = bbase;
  unsigned* eds = bbase + 1024;
  unsigned* eds2 = bbase + 1536;
  const int W = isz[n * 2 + 1], H = isz[n * 2 + 0];
  int cw = (W + 31) >> 5; if (cw < 128) cw = 128;
  int ch = (H + 31) >> 5; if (ch < 128) ch = 128;
  const int cols = (W + cw - 1) / cw;
  const int rows = (H + ch - 1) / ch;
  const float icw = 1.0f / (float)cw, ich = 1.0f / (float)ch;
  ccount[tid] = 0u;
  if (tid == 0) ecl = 0u;
  __syncthreads();
  int mycell = -1;
  if (tid < TOPK && ssc[tid] > NEGV * 0.5f) {
    float4 b = sb[tid];
    int cx = (int)((b.x + b.z) * 0.5f * icw);
    int cy = (int)((b.y + b.w) * 0.5f * ich);
    cx = cx < 0 ? 0 : (cx > cols - 1 ? cols - 1 : cx);
    cy = cy < 0 ? 0 : (cy > rows - 1 ? rows - 1 : cy);
    mycell = cy * cols + cx;
    atomicAdd(&ccount[mycell], 1u);
  }
  __syncthreads();
  {  // ascending exclusive scan over 1024 cells
    unsigned v = ccount[tid];
    unsigned inc = v;
#pragma unroll
    for (int d = 1; d < 64; d <<= 1) {
      unsigned o = __shfl_up(inc, d, 64);
      if (lane >= d) inc += o;
    }
    if (lane == 63) wsum[wid] = inc;
    __syncthreads();
    if (tid < 64) {
      unsigned vv = (tid < 16) ? wsum[tid] : 0u;
      unsigned i2 = vv;
#pragma unroll
      for (int d = 1; d < 16; d <<= 1) {
        unsigned o = __shfl_up(i2, d, 64);
        if (tid >= d) i2 += o;
      }
      if (tid < 16) wsum[tid] = i2 - vv;
    }
    __syncthreads();
    cbase[tid] = inc - v + wsum[wid];
  }
  __syncthreads();
  ccount[tid] = 0u;
  __syncthreads();
  if (mycell >= 0) {
    unsigned pos = cbase[mycell] + atomicAdd(&ccount[mycell], 1u);
    cidx[pos] = (unsigned)tid;
  }
  __syncthreads();
  if (mycell >= 0) {  // query 3x3 neighborhood for i<j with IoU>0.6
    const int j = tid;
    float4 bj = sb[j];
    float aj = (bj.z - bj.x) * (bj.w - bj.y);
    int cx = mycell % cols, cy = mycell / cols;
    int x0 = cx > 0 ? cx - 1 : 0, x1c = cx < cols - 1 ? cx + 1 : cols - 1;
    int y0 = cy > 0 ? cy - 1 : 0, y1c = cy < rows - 1 ? cy + 1 : rows - 1;
    for (int yy = y0; yy <= y1c; ++yy) {
      for (int xx = x0; xx <= x1c; ++xx) {
        unsigned c = (unsigned)(yy * cols + xx);
        unsigned b0 = cbase[c], cnt = ccount[c];
        for (unsigned k2 = 0; k2 < cnt; ++k2) {
          unsigned i = cidx[b0 + k2];
          if (i >= (unsigned)j) continue;
          float4 bi = sb[i];
          float ai = (bi.z - bi.x) * (bi.w - bi.y);
          float ltx = fmaxf(bi.x, bj.x), lty = fmaxf(bi.y, bj.y);
          float rbx = fminf(bi.z, bj.z), rby = fminf(bi.w, bj.w);
          float wv = fmaxf(rbx - ltx, 0.0f), hv = fmaxf(rby - lty, 0.0f);
          float inter = wv * hv;
          float iou = inter / (ai + aj - inter + 1e-9f);
          if (iou > 0.6f) {
            unsigned p2 = atomicAdd(&ecl, 1u);  // LDS atomic, rare
            if (p2 < EDS_CAP) eds[p2] = (i << 10) | (unsigned)j;
          }
        }
      }
    }
  }
  __syncthreads();
  // ---- sort edges (rank, unique keys) + exact greedy ----
  unsigned E = ecl; if (E > EDS_CAP) E = EDS_CAP;
  for (int k = tid; k < TOPK; k += 1024) kept[k] = 1;
  __syncthreads();
  for (int e = tid; e < (int)E; e += 1024) {
    unsigned v = eds[e];
    unsigned r = 0;
    for (unsigned t = 0; t < E; ++t) r += (eds[t] < v) ? 1u : 0u;
    eds2[r] = v;
  }
  __syncthreads();
  if (tid == 0) {  // kept[i] final before any edge (i,*) applied
    for (int e = 0; e < (int)E; ++e) {
      unsigned i2 = eds2[e] >> 10, j2 = eds2[e] & 1023u;
      if (kept[i2]) kept[j2] = 0;
    }
  }
  __syncthreads();
  // ---- select first 100 kept (wave0 shfl-scan) + write out ----
  if (tid < 100) sel[tid] = -1;
  __syncthreads();
  if (tid < 64) {
    int c0 = tid * 16;
    int c1 = c0 + 16; if (c1 > TOPK) c1 = TOPK;
    int cnt = 0;
    for (int e = c0; e < c1; ++e)
      if (kept[e] && ssc[e] > NEGV * 0.5f) cnt++;
    int inc = cnt;
#pragma unroll
    for (int d = 1; d < 64; d <<= 1) {
      int o = __shfl_up(inc, d, 64);
      if (tid >= d) inc += o;
    }
    unsigned r = (unsigned)(inc - cnt);
    for (int e = c0; e < c1; ++e) {
      if (kept[e] && ssc[e] > NEGV * 0.5f) {
        if (r < 100u) sel[r] = e;
        r++;
      }
    }
  }
  __syncthreads();
  for (int k = tid; k < 100; k += 1024) {
    int s = sel[k];
    float x1 = 0.f, y1 = 0.f, x2 = 0.f, y2 = 0.f, sc = 0.f, lab = 0.f, fv = 0.f;
    if (s >= 0) {
      float4 b = sb[s];
      x1 = b.x; y1 = b.y; x2 = b.z; y2 = b.w;
      sc = ssc[s]; lab = 1.0f; fv = 1.0f;
    }
    int o = (n * 100 + k) * 5;
    out[o + 0] = x1; out[o + 1] = y1; out[o + 2] = x2; out[o + 3] = y2; out[o + 4] = sc;
    out[NIMG * 500 + n * 100 + k] = lab;
    out[NIMG * 600 + n * 100 + k] = fv;
  }
}

extern "C" void kernel_launch(void* const* d_in, const int* in_sizes, int n_in,
                              void* d_out, int out_size, void* d_ws, size_t ws_size,
                              hipStream_t stream) {
  // inputs: 0=locations (unused), 1=box_cls, 2=box_regression, 3=centerness, 4=image_sizes
  const float4* cls4 = (const float4*)d_in[1];
  const float* reg = (const float*)d_in[2];
  const float4* ctr4 = (const float4*)d_in[3];
  const int* isz = (const int*)d_in[4];
  float* out = (float*)d_out;
  uint8_t* w = (uint8_t*)d_ws;

  const size_t NSLOT = (size_t)NIMG * SCAN_BLOCKS * PCAP;
  uint8_t* p = w;
  float* preval = (float*)p;      p += NSLOT * 4;    // 3.9 MB
  unsigned* pregi = (unsigned*)p; p += NSLOT * 4;    // 3.9 MB
  float4* prebox = (float4*)p;    p += NSLOT * 16;   // 15.7 MB
  unsigned* pcnt = (unsigned*)p;  p += (size_t)NIMG * SCAN_BLOCKS * 4;
  (void)ws_size;  // ~23.6 MB needed

  dim3 g1(SCAN_BLOCKS, NIMG);
  k_scanstore<<<g1, SCAN_THREADS, 0, stream>>>(cls4, ctr4, reg, isz,
                                               preval, pregi, prebox, pcnt);
  k_fcr_nms<<<NIMG, 1024, 0, stream>>>(preval, pregi, prebox, pcnt, isz, out);
}

// Round 16
// 49.711 us; speedup vs baseline: 1.1421x; 1.1421x over previous
//
#include <hip/hip_runtime.h>
#include <cstdint>

// FCOS post-processor, MI355X — round 16.
// R15 postmortem: k_fcr_nms stuck at 39.6us with ~0 HBM traffic and 2% VALU —
// latency-chain bound: each flatten iteration = 6-deep LDS binary search ->
// dependent global load -> LDS atomic (~900cy serial), ~8 grid-stride iters x
// 2 passes on 1 block/CU. Fixes: (1) load-first batching (searches/loads for 8
// elements issued before any consume); (2) prelist local-suffix LS 128->64
// (P ~8200 -> ~4700; Poisson(16.7) tail at 64 ~ 1e-14/block — exactness still
// enforced by exact-B2 filter + exact (val,idx) rank on a superset).
//
//  k_scanstore : read cls+ctr once (31 MB). Per block: 512-bin LDS hist ->
//                local thresh (suffix>=64) -> prelist; gather reg + decode
//                + clip + keep_size -> (val, gi, box) per entry.
//  k_fcr_nms   : per image, 1024 thr: offs-scan; pass1 (batched) bucket
//                2048-hist of preval -> boundary bucket B2; bases; pass2
//                (batched) scatter cand -> sk + skbox; exact rank; spatial-
//                hash NMS; exact greedy; select 100; write.

#define NIMG 16
#define WW 608
#define HW 243200
#define NF4 60800          // HW/4
#define TOPK 1000
#define NBINS 512          // scanstore local hist bins
#define NB2 2048           // fine buckets (selection + sort)
#define SCAN_BLOCKS 60     // per image
#define SCAN_THREADS 256
#define F4_PER_BLOCK 1024  // 60*1024*4 = 245760 >= 243200
#define LS 64              // local-suffix constant for prelist threshold
#define PCAP 256           // prelist cap per scan block (~78 expected)
#define MCAP 2048          // candidate cap per image (expected ~1005)
#define EDS_CAP 512        // edge cap (observed ~15/image)
#define UNROLL_P 8         // flatten batch depth (covers P <= 8192 per step)
#define NEGV (-1e9f)

__device__ __forceinline__ float sigm(float x) { return 1.0f / (1.0f + expf(-x)); }

__device__ __forceinline__ int binof(float v) {
  if (!(v > 0.0f)) return 0;
  int b = (int)(v * (float)NBINS);
  return b > (NBINS - 1) ? (NBINS - 1) : b;
}

__device__ __forceinline__ int bucketof(float v) {
  if (!(v > 0.0f)) return 0;
  int b = (int)(v * (float)NB2);
  return b > (NB2 - 1) ? (NB2 - 1) : b;
}

// wave0 (tid<64): *outbs = max b with suffix_bins(b) >= T, else 0 (512 bins).
__device__ __forceinline__ void find_thresh_bin(const unsigned* h, const unsigned* chunk,
                                                unsigned T, unsigned* outbs, int tid) {
  unsigned v = (tid < 32) ? chunk[tid] : 0u;
  unsigned inc = v;
#pragma unroll
  for (int d = 1; d < 32; d <<= 1) {
    unsigned o = __shfl_down(inc, d, 64);
    if (tid + d < 32) inc += o;
  }
  unsigned long long m = __ballot((tid < 32) && (inc >= T));
  if (m == 0ull) { if (tid == 0) *outbs = 0u; return; }
  int cc = 63 - __clzll(m);
  unsigned above = __shfl(inc, cc) - chunk[cc];
  unsigned v2 = (tid < 16) ? h[cc * 16 + tid] : 0u;
  unsigned inc2 = v2;
#pragma unroll
  for (int d = 1; d < 16; d <<= 1) {
    unsigned o = __shfl_down(inc2, d, 64);
    if (tid + d < 16) inc2 += o;
  }
  unsigned long long m2 = __ballot((tid < 16) && (above + inc2 >= T));
  int bb = (m2 != 0ull) ? (63 - __clzll(m2)) : 0;
  if (tid == 0) *outbs = (unsigned)(cc * 16 + bb);
}

__global__ __launch_bounds__(SCAN_THREADS) void k_scanstore(
    const float4* __restrict__ cls, const float4* __restrict__ ctr,
    const float* __restrict__ reg, const int* __restrict__ isz,
    float* __restrict__ preval, unsigned* __restrict__ pregi,
    float4* __restrict__ prebox, unsigned* __restrict__ pcnt) {
  __shared__ unsigned lh[NBINS];
  __shared__ float lval[PCAP];
  __shared__ unsigned lgi[PCAP];
  __shared__ unsigned chunk[NBINS / 16];
  __shared__ unsigned sLb, pcl;
  const int tid = threadIdx.x;
  for (int b = tid; b < NBINS; b += SCAN_THREADS) lh[b] = 0u;
  if (tid == 0) pcl = 0u;
  __syncthreads();
  const int n = blockIdx.y;
  const float4* c4 = cls + (size_t)n * NF4;
  const float4* t4 = ctr + (size_t)n * NF4;
  const int base = blockIdx.x * F4_PER_BLOCK;
  float4 cv[4], tv[4];
  float smr[16];
  bool ok[4];
#pragma unroll
  for (int e = 0; e < 4; ++e) {
    int i = base + e * SCAN_THREADS + tid;
    ok[e] = (i < NF4);
    if (ok[e]) { cv[e] = c4[i]; tv[e] = t4[i]; }
  }
#pragma unroll
  for (int e = 0; e < 4; ++e) {
    const float* cc = (const float*)&cv[e];
    const float* tt = (const float*)&tv[e];
#pragma unroll
    for (int k = 0; k < 4; ++k) {
      float sm = NEGV;
      if (ok[e]) {
        float sc = sigm(cc[k]);
        sm = (sc > 0.05f) ? sc * sigm(tt[k]) : NEGV;
        atomicAdd(&lh[binof(sm)], 1u);  // LDS atomic
      }
      smr[e * 4 + k] = sm;
    }
  }
  __syncthreads();
  if (tid < NBINS / 16) {
    unsigned s = 0;
    for (int k = 0; k < 16; ++k) s += lh[tid * 16 + k];
    chunk[tid] = s;
  }
  __syncthreads();
  if (tid < 64) find_thresh_bin(lh, chunk, LS, &sLb, tid);
  __syncthreads();
  const unsigned Lb = sLb;
#pragma unroll
  for (int e = 0; e < 4; ++e) {
    if (ok[e]) {
#pragma unroll
      for (int k = 0; k < 4; ++k) {
        float sm = smr[e * 4 + k];
        if ((unsigned)binof(sm) >= Lb) {
          unsigned gi = (unsigned)((base + e * SCAN_THREADS + tid) * 4 + k);
          unsigned p = atomicAdd(&pcl, 1u);  // LDS atomic
          if (p < PCAP) { lval[p] = sm; lgi[p] = gi; }
        }
      }
    }
  }
  __syncthreads();
  const int bslot = n * SCAN_BLOCKS + blockIdx.x;
  unsigned m = pcl; if (m > PCAP) m = PCAP;
  // gather reg + decode + clip + keep_size; 960 blocks hide the scattered loads
  const float wmax = (float)(isz[n * 2 + 1] - 1);
  const float hmax = (float)(isz[n * 2 + 0] - 1);
  const float* rg = reg + (size_t)n * 4 * HW;
  const size_t gbase = (size_t)bslot * PCAP;
  for (unsigned k = tid; k < m; k += SCAN_THREADS) {
    unsigned gi = lgi[k];
    float val = lval[k];
    int wx = (int)gi % WW, hy = (int)gi / WW;
    float lx = (float)(wx * 8 + 4), ly = (float)(hy * 8 + 4);
    float l = rg[0 * HW + gi], tt = rg[1 * HW + gi];
    float rr = rg[2 * HW + gi], bb = rg[3 * HW + gi];
    float x1 = lx - l, y1 = ly - tt, x2 = lx + rr, y2 = ly + bb;
    x1 = fminf(fmaxf(x1, 0.0f), wmax);
    x2 = fminf(fmaxf(x2, 0.0f), wmax);
    y1 = fminf(fmaxf(y1, 0.0f), hmax);
    y2 = fminf(fmaxf(y2, 0.0f), hmax);
    bool valid = (((x2 - x1 + 1.0f) >= 0.0f) && ((y2 - y1 + 1.0f) >= 0.0f));
    float4 bx = valid ? make_float4(x1, y1, x2, y2)
                      : make_float4(-1.f, -1.f, -1.f, -1.f);  // zero-area, x<0 flag
    preval[gbase + k] = val;
    pregi[gbase + k] = gi;
    prebox[gbase + k] = bx;
  }
  if (tid == 0) pcnt[bslot] = m;
}

// selection + rank + spatial-hash NMS + output: one 1024-thread block per image.
__global__ __launch_bounds__(1024) void k_fcr_nms(
    const float* __restrict__ preval, const unsigned* __restrict__ pregi,
    const float4* __restrict__ prebox, const unsigned* __restrict__ pcnt,
    const int* __restrict__ isz, float* __restrict__ out) {
  __shared__ __align__(16) unsigned long long smemA[2816];  // 22.5 KB: sb/ssc/kept/sel
  __shared__ __align__(16) unsigned long long sk[MCAP];     // 16 KB
  __shared__ __align__(16) float4 skbox[MCAP];              // 32 KB
  __shared__ unsigned bh[NB2];                              // 8 KB
  __shared__ unsigned bbase[NB2];                           // 8 KB
  __shared__ unsigned chunk[32];
  __shared__ unsigned offs[SCAN_BLOCKS + 1];
  __shared__ unsigned wsum[16];
  __shared__ unsigned sB2, mc, ecl;
  const int n = blockIdx.x;
  const int tid = threadIdx.x;
  const int wid = tid >> 6, lane = tid & 63;

  for (int b = tid; b < NB2; b += 1024) bh[b] = 0u;
  if (tid < 64) {  // wave0: shfl-scan prelist counts
    int l = tid;
    int v = (l < SCAN_BLOCKS) ? (int)pcnt[n * SCAN_BLOCKS + l] : 0;
    int inc = v;
#pragma unroll
    for (int d = 1; d < 64; d <<= 1) {
      int o = __shfl_up(inc, d, 64);
      if (l >= d) inc += o;
    }
    if (l < SCAN_BLOCKS) offs[l + 1] = (unsigned)inc;
    if (l == 0) offs[0] = 0u;
  }
  __syncthreads();
  const unsigned P = offs[SCAN_BLOCKS];
  const size_t ibase = (size_t)n * SCAN_BLOCKS * PCAP;
  // ---- pass 1 (batched load-first): bucket hist of all prelist vals ----
  for (unsigned p0 = 0; p0 < P; p0 += UNROLL_P * 1024u) {
    float vbuf[UNROLL_P];
    bool okp[UNROLL_P];
#pragma unroll
    for (int u = 0; u < UNROLL_P; ++u) {
      unsigned p = p0 + (unsigned)tid + (unsigned)u * 1024u;
      okp[u] = (p < P);
      if (okp[u]) {
        int lo = 0, hi = SCAN_BLOCKS - 1;
        while (lo < hi) {
          int mid = (lo + hi + 1) >> 1;
          if (offs[mid] <= p) lo = mid; else hi = mid - 1;
        }
        vbuf[u] = preval[ibase + (size_t)lo * PCAP + (p - offs[lo])];
      }
    }
#pragma unroll
    for (int u = 0; u < UNROLL_P; ++u)
      if (okp[u]) atomicAdd(&bh[bucketof(vbuf[u])], 1u);
  }
  __syncthreads();
  // ---- boundary bucket B2 = max bucket with suffix >= TOPK ----
  if (tid < 32) {
    unsigned s = 0;
    const int b0 = tid * 64;
    for (int k = 0; k < 64; ++k) s += bh[b0 + k];
    chunk[tid] = s;
  }
  __syncthreads();
  if (tid < 64) {
    unsigned v = (tid < 32) ? chunk[tid] : 0u;
    unsigned inc = v;
#pragma unroll
    for (int d = 1; d < 32; d <<= 1) {
      unsigned o = __shfl_down(inc, d, 64);
      if (tid + d < 32) inc += o;
    }
    unsigned long long m = __ballot((tid < 32) && (inc >= TOPK));
    int cc = (m != 0ull) ? (63 - __clzll(m)) : 0;
    unsigned above = (m != 0ull) ? (__shfl(inc, cc) - chunk[cc]) : 0u;
    unsigned inc2 = bh[cc * 64 + tid];
#pragma unroll
    for (int d = 1; d < 64; d <<= 1) {
      unsigned o = __shfl_down(inc2, d, 64);
      if (tid + d < 64) inc2 += o;
    }
    unsigned long long m2 = __ballot(above + inc2 >= TOPK);
    int bb = (m2 != 0ull) ? (63 - __clzll(m2)) : 0;
    if (tid == 0) sB2 = (m != 0ull) ? (unsigned)(cc * 64 + bb) : 0u;
  }
  __syncthreads();
  const unsigned B2 = sB2;
  // ---- descending bucket bases: bbase[b] = #vals in buckets > b ----
  {
    int g0 = tid * 2, g1 = g0 + 1;
    unsigned a0 = bh[NB2 - 1 - g0];
    unsigned a1 = bh[NB2 - 1 - g1];
    unsigned pair = a0 + a1;
    unsigned inc = pair;
#pragma unroll
    for (int d = 1; d < 64; d <<= 1) {
      unsigned o = __shfl_up(inc, d, 64);
      if (lane >= d) inc += o;
    }
    if (lane == 63) wsum[wid] = inc;
    __syncthreads();
    if (tid < 64) {
      unsigned v = (tid < 16) ? wsum[tid] : 0u;
      unsigned i2 = v;
#pragma unroll
      for (int d = 1; d < 16; d <<= 1) {
        unsigned o = __shfl_up(i2, d, 64);
        if (tid >= d) i2 += o;
      }
      if (tid < 16) wsum[tid] = i2 - v;
    }
    __syncthreads();
    unsigned excl = inc - pair + wsum[wid];
    bbase[NB2 - 1 - g0] = excl;
    bbase[NB2 - 1 - g1] = excl + a0;
  }
  __syncthreads();
  if (tid == 0) {
    unsigned mm = bbase[B2] + bh[B2];
    mc = (mm > MCAP) ? MCAP : mm;
  }
  for (int b = tid; b < NB2; b += 1024) bh[b] = 0u;  // scatter counters
  __syncthreads();
  const unsigned M = mc;
  // ---- pass 2 (batched): scatter candidates (bucket >= B2) -> sk + skbox ----
  for (unsigned p0 = 0; p0 < P; p0 += UNROLL_P * 1024u) {
    float vbuf[UNROLL_P];
    size_t idxb[UNROLL_P];
    bool okp[UNROLL_P];
#pragma unroll
    for (int u = 0; u < UNROLL_P; ++u) {
      unsigned p = p0 + (unsigned)tid + (unsigned)u * 1024u;
      okp[u] = (p < P);
      if (okp[u]) {
        int lo = 0, hi = SCAN_BLOCKS - 1;
        while (lo < hi) {
          int mid = (lo + hi + 1) >> 1;
          if (offs[mid] <= p) lo = mid; else hi = mid - 1;
        }
        idxb[u] = ibase + (size_t)lo * PCAP + (p - offs[lo]);
        vbuf[u] = preval[idxb[u]];
      }
    }
#pragma unroll
    for (int u = 0; u < UNROLL_P; ++u) {
      if (okp[u]) {
        int b = bucketof(vbuf[u]);
        if ((unsigned)b >= B2) {
          unsigned gi = pregi[idxb[u]];
          unsigned pos = bbase[b] + atomicAdd(&bh[b], 1u);
          if (pos < MCAP) {
            sk[pos] = ((unsigned long long)__float_as_uint(vbuf[u]) << 32) |
                      (unsigned long long)(~gi);
            skbox[pos] = prebox[idxb[u]];
          }
        }
      }
    }
  }
  // ---- prefill output boxes/scores (overlay smemA) ----
  float4* sb = (float4*)smemA;                                   // 16000 B
  float* ssc = (float*)((char*)smemA + 16384);                   // 4000 B
  unsigned char* kept = (unsigned char*)((char*)smemA + 20480);  // 1000 B
  int* sel = (int*)((char*)smemA + 21600);                       // 400 B
  if (tid < TOPK) { sb[tid] = make_float4(0.f, 0.f, 0.f, 0.f); ssc[tid] = NEGV; }
  __syncthreads();
  // ---- exact rank (bucket base + same-bucket u64 count) + place into sb ----
  for (unsigned s = tid; s < M; s += 1024) {
    const unsigned long long mykey = sk[s];
    const float val = __uint_as_float((unsigned)(mykey >> 32));
    int b = bucketof(val);
    unsigned beg = bbase[b];
    unsigned end = (b > 0) ? bbase[b - 1] : M;
    if (end > M) end = M;
    unsigned rank = beg;
    for (unsigned t = beg; t < end; ++t) rank += (sk[t] > mykey) ? 1u : 0u;
    if (rank >= TOPK) continue;
    float4 bx = skbox[s];
    sb[rank] = bx;
    ssc[rank] = (bx.x < 0.0f) ? NEGV : val;  // keep_size-invalid -> masked score
  }
  __syncthreads();
  // ---- spatial-hash NMS (bh/bbase free): boxes <128px -> 3x3 cell checks ----
  unsigned* ccount = bh;
  unsigned* cidx = bh + 1024;
  unsigned* cbase = bbase;
  unsigned* eds = bbase + 1024;
  unsigned* eds2 = bbase + 1536;
  const int W = isz[n * 2 + 1], H = isz[n * 2 + 0];
  int cw = (W + 31) >> 5; if (cw < 128) cw = 128;
  int ch = (H + 31) >> 5; if (ch < 128) ch = 128;
  const int cols = (W + cw - 1) / cw;
  const int rows = (H + ch - 1) / ch;
  const float icw = 1.0f / (float)cw, ich = 1.0f / (float)ch;
  ccount[tid] = 0u;
  if (tid == 0) ecl = 0u;
  __syncthreads();
  int mycell = -1;
  if (tid < TOPK && ssc[tid] > NEGV * 0.5f) {
    float4 b = sb[tid];
    int cx = (int)((b.x + b.z) * 0.5f * icw);
    int cy = (int)((b.y + b.w) * 0.5f * ich);
    cx = cx < 0 ? 0 : (cx > cols - 1 ? cols - 1 : cx);
    cy = cy < 0 ? 0 : (cy > rows - 1 ? rows - 1 : cy);
    mycell = cy * cols + cx;
    atomicAdd(&ccount[mycell], 1u);
  }
  __syncthreads();
  {  // ascending exclusive scan over 1024 cells
    unsigned v = ccount[tid];
    unsigned inc = v;
#pragma unroll
    for (int d = 1; d < 64; d <<= 1) {
      unsigned o = __shfl_up(inc, d, 64);
      if (lane >= d) inc += o;
    }
    if (lane == 63) wsum[wid] = inc;
    __syncthreads();
    if (tid < 64) {
      unsigned vv = (tid < 16) ? wsum[tid] : 0u;
      unsigned i2 = vv;
#pragma unroll
      for (int d = 1; d < 16; d <<= 1) {
        unsigned o = __shfl_up(i2, d, 64);
        if (tid >= d) i2 += o;
      }
      if (tid < 16) wsum[tid] = i2 - vv;
    }
    __syncthreads();
    cbase[tid] = inc - v + wsum[wid];
  }
  __syncthreads();
  ccount[tid] = 0u;
  __syncthreads();
  if (mycell >= 0) {
    unsigned pos = cbase[mycell] + atomicAdd(&ccount[mycell], 1u);
    cidx[pos] = (unsigned)tid;
  }
  __syncthreads();
  if (mycell >= 0) {  // query 3x3 neighborhood for i<j with IoU>0.6
    const int j = tid;
    float4 bj = sb[j];
    float aj = (bj.z - bj.x) * (bj.w - bj.y);
    int cx = mycell % cols, cy = mycell / cols;
    int x0 = cx > 0 ? cx - 1 : 0, x1c = cx < cols - 1 ? cx + 1 : cols - 1;
    int y0 = cy > 0 ? cy - 1 : 0, y1c = cy < rows - 1 ? cy + 1 : rows - 1;
    for (int yy = y0; yy <= y1c; ++yy) {
      for (int xx = x0; xx <= x1c; ++xx) {
        unsigned c = (unsigned)(yy * cols + xx);
        unsigned b0 = cbase[c], cnt = ccount[c];
        for (unsigned k2 = 0; k2 < cnt; ++k2) {
          unsigned i = cidx[b0 + k2];
          if (i >= (unsigned)j) continue;
          float4 bi = sb[i];
          float ai = (bi.z - bi.x) * (bi.w - bi.y);
          float ltx = fmaxf(bi.x, bj.x), lty = fmaxf(bi.y, bj.y);
          float rbx = fminf(bi.z, bj.z), rby = fminf(bi.w, bj.w);
          float wv = fmaxf(rbx - ltx, 0.0f), hv = fmaxf(rby - lty, 0.0f);
          float inter = wv * hv;
          float iou = inter / (ai + aj - inter + 1e-9f);
          if (iou > 0.6f) {
            unsigned p2 = atomicAdd(&ecl, 1u);  // LDS atomic, rare
            if (p2 < EDS_CAP) eds[p2] = (i << 10) | (unsigned)j;
          }
        }
      }
    }
  }
  __syncthreads();
  // ---- sort edges (rank, unique keys) + exact greedy ----
  unsigned E = ecl; if (E > EDS_CAP) E = EDS_CAP;
  for (int k = tid; k < TOPK; k += 1024) kept[k] = 1;
  __syncthreads();
  for (int e = tid; e < (int)E; e += 1024) {
    unsigned v = eds[e];
    unsigned r = 0;
    for (unsigned t = 0; t < E; ++t) r += (eds[t] < v) ? 1u : 0u;
    eds2[r] = v;
  }
  __syncthreads();
  if (tid == 0) {  // kept[i] final before any edge (i,*) applied
    for (int e = 0; e < (int)E; ++e) {
      unsigned i2 = eds2[e] >> 10, j2 = eds2[e] & 1023u;
      if (kept[i2]) kept[j2] = 0;
    }
  }
  __syncthreads();
  // ---- select first 100 kept (wave0 shfl-scan) + write out ----
  if (tid < 100) sel[tid] = -1;
  __syncthreads();
  if (tid < 64) {
    int c0 = tid * 16;
    int c1 = c0 + 16; if (c1 > TOPK) c1 = TOPK;
    int cnt = 0;
    for (int e = c0; e < c1; ++e)
      if (kept[e] && ssc[e] > NEGV * 0.5f) cnt++;
    int inc = cnt;
#pragma unroll
    for (int d = 1; d < 64; d <<= 1) {
      int o = __shfl_up(inc, d, 64);
      if (tid >= d) inc += o;
    }
    unsigned r = (unsigned)(inc - cnt);
    for (int e = c0; e < c1; ++e) {
      if (kept[e] && ssc[e] > NEGV * 0.5f) {
        if (r < 100u) sel[r] = e;
        r++;
      }
    }
  }
  __syncthreads();
  for (int k = tid; k < 100; k += 1024) {
    int s = sel[k];
    float x1 = 0.f, y1 = 0.f, x2 = 0.f, y2 = 0.f, sc = 0.f, lab = 0.f, fv = 0.f;
    if (s >= 0) {
      float4 b = sb[s];
      x1 = b.x; y1 = b.y; x2 = b.z; y2 = b.w;
      sc = ssc[s]; lab = 1.0f; fv = 1.0f;
    }
    int o = (n * 100 + k) * 5;
    out[o + 0] = x1; out[o + 1] = y1; out[o + 2] = x2; out[o + 3] = y2; out[o + 4] = sc;
    out[NIMG * 500 + n * 100 + k] = lab;
    out[NIMG * 600 + n * 100 + k] = fv;
  }
}

extern "C" void kernel_launch(void* const* d_in, const int* in_sizes, int n_in,
                              void* d_out, int out_size, void* d_ws, size_t ws_size,
                              hipStream_t stream) {
  // inputs: 0=locations (unused), 1=box_cls, 2=box_regression, 3=centerness, 4=image_sizes
  const float4* cls4 = (const float4*)d_in[1];
  const float* reg = (const float*)d_in[2];
  const float4* ctr4 = (const float4*)d_in[3];
  const int* isz = (const int*)d_in[4];
  float* out = (float*)d_out;
  uint8_t* w = (uint8_t*)d_ws;

  const size_t NSLOT = (size_t)NIMG * SCAN_BLOCKS * PCAP;
  uint8_t* p = w;
  float* preval = (float*)p;      p += NSLOT * 4;    // 983 KB
  unsigned* pregi = (unsigned*)p; p += NSLOT * 4;    // 983 KB
  float4* prebox = (float4*)p;    p += NSLOT * 16;   // 3.9 MB
  unsigned* pcnt = (unsigned*)p;  p += (size_t)NIMG * SCAN_BLOCKS * 4;
  (void)ws_size;  // ~5.9 MB needed

  dim3 g1(SCAN_BLOCKS, NIMG);
  k_scanstore<<<g1, SCAN_THREADS, 0, stream>>>(cls4, ctr4, reg, isz,
                                               preval, pregi, prebox, pcnt);
  k_fcr_nms<<<NIMG, 1024, 0, stream>>>(preval, pregi, prebox, pcnt, isz, out);
}